// Round 2
// baseline (363.443 us; speedup 1.0000x reference)
//
#include <hip/hip_runtime.h>
#include <math.h>

// GraphSAGE fused inference, MI355X.
// Key trick: fc1 is linear (no bias/activation) and agg0 = mean over n0 of h1,
// so agg0 = concat(mean(e_n), mean_all(e_nn)) @ W1 — no per-neighbor GEMM needed.
//
// R2: __launch_bounds__(256,4) (R1's (256,8) capped VGPR at 64 -> suspected
// scratch spills in the gather loop); unroll-8 gather with 2 independent
// accumulators for ~8 outstanding loads/thread.

constexpr int D   = 64;    // embed dim
constexpr int N0  = 10;
constexpr int N1  = 25;
constexpr int NN  = N0 * N1;   // 250
constexpr int H1  = 128;
constexpr int H0  = 128;
constexpr int K0  = D + H1;    // 192 (fc0 input dim)
constexpr int BPB = 2;         // batch rows per block
constexpr int NT  = 256;       // threads per block

__global__ __launch_bounds__(NT, 4) void sage_fused(
    const int*   __restrict__ inputs,   // [B]
    const int*   __restrict__ neigh0,   // [B, 10]
    const int*   __restrict__ neigh1,   // [B, 10, 25]
    const float* __restrict__ embed,    // [NODE_CNT+1, 64]
    const float* __restrict__ W1,       // [128, 128]
    const float* __restrict__ W0,       // [192, 128]
    const float* __restrict__ b0,       // [128]
    float*       __restrict__ out)      // [B, 128]
{
    __shared__ int   s_idx1[BPB * NN];       // 500 ints
    __shared__ int   s_idx0[BPB * N0];       // 20 ints
    __shared__ int   s_in[BPB];
    __shared__ float part_nn[16][D];         // 4 KB
    __shared__ float part_en[16][D];         // 4 KB
    __shared__ float xbar[BPB][2 * D];       // [r][128] : [e_n mean | nn mean]
    __shared__ float x0s[BPB][K0];           // [r][192] : [e_v | agg0]
    __shared__ float p2[2][BPB][H1];         // half-K partial sums

    const int t     = threadIdx.x;
    const int bbase = blockIdx.x * BPB;

    // ---- stage indices into LDS (coalesced) ----
    for (int i = t; i < BPB * NN; i += NT) s_idx1[i] = neigh1[bbase * NN + i];
    if (t < BPB * N0) s_idx0[t] = neigh0[bbase * N0 + t];
    if (t < BPB)      s_in[t]   = inputs[bbase + t];
    __syncthreads();

    // ---- phase 1: gather + accumulate ----
    // thread -> (slot s, 16B column chunk). 16 lanes cover one 256B row.
    const int c4lane = t & 15;         // 0..15
    const int s      = t >> 4;         // slot 0..15
    const int r      = s & (BPB - 1);  // batch row within block
    const int ss     = s >> 1;         // 0..7 : slot index within row
    const int cOff   = c4lane * 4;     // float column offset

    // NN=250 rows per batch-row, 8 slots -> ~31 iters/thread.
    // Two independent accumulators + unroll 8 => deep vmcnt pipeline.
    float4 acc_a = make_float4(0.f, 0.f, 0.f, 0.f);
    float4 acc_b = make_float4(0.f, 0.f, 0.f, 0.f);
    {
        const int* idxp = &s_idx1[r * NN];
        int i = ss;
        #pragma unroll 1
        for (; i + 8 * 8 <= NN + ss; i += 16) {  // pairs of strided iters
            const int i0 = i, i1 = i + 8;
            const float4 v0 = *(const float4*)(embed + (size_t)idxp[i0] * D + cOff);
            const float4 v1 = *(const float4*)(embed + (size_t)idxp[i1] * D + cOff);
            acc_a.x += v0.x; acc_a.y += v0.y; acc_a.z += v0.z; acc_a.w += v0.w;
            acc_b.x += v1.x; acc_b.y += v1.y; acc_b.z += v1.z; acc_b.w += v1.w;
        }
        #pragma unroll
        for (; i < NN; i += 8) {
            const float4 v = *(const float4*)(embed + (size_t)idxp[i] * D + cOff);
            acc_a.x += v.x; acc_a.y += v.y; acc_a.z += v.z; acc_a.w += v.w;
        }
    }
    float4 sum_nn = make_float4(acc_a.x + acc_b.x, acc_a.y + acc_b.y,
                                acc_a.z + acc_b.z, acc_a.w + acc_b.w);

    float4 sum_en = make_float4(0.f, 0.f, 0.f, 0.f);
    #pragma unroll
    for (int i = ss; i < N0; i += 8) {
        const int idx = s_idx0[r * N0 + i];
        const float4 v = *(const float4*)(embed + (size_t)idx * D + cOff);
        sum_en.x += v.x; sum_en.y += v.y; sum_en.z += v.z; sum_en.w += v.w;
    }
    if (ss == 0) {  // e_v row for batch row r
        const int idx = s_in[r];
        const float4 v = *(const float4*)(embed + (size_t)idx * D + cOff);
        *(float4*)&x0s[r][cOff] = v;
    }
    *(float4*)&part_nn[s][cOff] = sum_nn;
    *(float4*)&part_en[s][cOff] = sum_en;
    __syncthreads();

    // ---- reduce partials -> xbar ----
    if (t < BPB * D) {
        const int rr = t >> 6;       // batch row
        const int c  = t & 63;       // column
        float snn = 0.f, sen = 0.f;
        #pragma unroll
        for (int q = 0; q < 16 / BPB; ++q) {
            snn += part_nn[rr + BPB * q][c];
            sen += part_en[rr + BPB * q][c];
        }
        xbar[rr][c]     = sen * (1.0f / N0);   // mean e_n
        xbar[rr][D + c] = snn * (1.0f / NN);   // mean e_nn (mean of means == mean of all)
    }
    __syncthreads();

    // ---- phase 2a: agg0 = xbar @ W1  (128x128 matvec per row) ----
    const int j    = t & 127;   // output column
    const int half = t >> 7;    // k-range half
    {
        float acc[BPB];
        #pragma unroll
        for (int r2 = 0; r2 < BPB; ++r2) acc[r2] = 0.f;
        const int kbase = half * 64;
        #pragma unroll 4
        for (int k4 = 0; k4 < 16; ++k4) {
            const int k = kbase + k4 * 4;
            float4 xv[BPB];
            #pragma unroll
            for (int r2 = 0; r2 < BPB; ++r2)
                xv[r2] = *(const float4*)&xbar[r2][k];
            const float wa = W1[(k + 0) * H1 + j];
            const float wb = W1[(k + 1) * H1 + j];
            const float wc = W1[(k + 2) * H1 + j];
            const float wd = W1[(k + 3) * H1 + j];
            #pragma unroll
            for (int r2 = 0; r2 < BPB; ++r2)
                acc[r2] += xv[r2].x * wa + xv[r2].y * wb + xv[r2].z * wc + xv[r2].w * wd;
        }
        #pragma unroll
        for (int r2 = 0; r2 < BPB; ++r2) p2[half][r2][j] = acc[r2];
    }
    __syncthreads();
    for (int idx = t; idx < BPB * H1; idx += NT) {
        const int rr = idx >> 7, jj = idx & 127;
        x0s[rr][D + jj] = p2[0][rr][jj] + p2[1][rr][jj];
    }
    __syncthreads();

    // ---- phase 2b: h0 = sigmoid(x0 @ W0 + b0)  (192x128 matvec per row) ----
    {
        float acc[BPB];
        #pragma unroll
        for (int r2 = 0; r2 < BPB; ++r2) acc[r2] = 0.f;
        const int kbase = half * 96;
        #pragma unroll 4
        for (int k4 = 0; k4 < 24; ++k4) {
            const int k = kbase + k4 * 4;
            float4 xv[BPB];
            #pragma unroll
            for (int r2 = 0; r2 < BPB; ++r2)
                xv[r2] = *(const float4*)&x0s[r2][k];
            const float wa = W0[(k + 0) * H0 + j];
            const float wb = W0[(k + 1) * H0 + j];
            const float wc = W0[(k + 2) * H0 + j];
            const float wd = W0[(k + 3) * H0 + j];
            #pragma unroll
            for (int r2 = 0; r2 < BPB; ++r2)
                acc[r2] += xv[r2].x * wa + xv[r2].y * wb + xv[r2].z * wc + xv[r2].w * wd;
        }
        #pragma unroll
        for (int r2 = 0; r2 < BPB; ++r2) p2[half][r2][j] = acc[r2];
    }
    __syncthreads();
    for (int idx = t; idx < BPB * H0; idx += NT) {
        const int rr = idx >> 7, jj = idx & 127;
        const float v = p2[0][rr][jj] + p2[1][rr][jj] + b0[jj];
        out[(size_t)(bbase + rr) * H0 + jj] = 1.0f / (1.0f + __expf(-v));
    }
}

extern "C" void kernel_launch(void* const* d_in, const int* in_sizes, int n_in,
                              void* d_out, int out_size, void* d_ws, size_t ws_size,
                              hipStream_t stream) {
    const int*   inputs = (const int*)  d_in[0];
    const int*   neigh0 = (const int*)  d_in[1];
    const int*   neigh1 = (const int*)  d_in[2];
    const float* embed  = (const float*)d_in[3];
    const float* W1     = (const float*)d_in[4];
    const float* W0     = (const float*)d_in[5];
    const float* b0     = (const float*)d_in[6];
    float*       out    = (float*)d_out;

    const int B = in_sizes[0];           // 4096
    const int nblocks = B / BPB;         // 2048
    sage_fused<<<dim3(nblocks), dim3(NT), 0, stream>>>(
        inputs, neigh0, neigh1, embed, W1, W0, b0, out);
}

// Round 3
// 361.601 us; speedup vs baseline: 1.0051x; 1.0051x over previous
//
#include <hip/hip_runtime.h>
#include <math.h>

// GraphSAGE fused inference, MI355X.
// fc1 is linear (no bias/act) and agg0 = mean_n0(h1)  =>
// agg0 = concat(mean(e_n over 10), mean(e_nn over all 250)) @ W1.
// Dominant cost: 4096*261 random 256B row gathers (~274 MB) — DRAM
// row-activation-bound (~2.6-2.9 TB/s ceiling for random 256B rows).
//
// R3: BPB=1 (4096 blocks, 2x memory-level parallelism), 4-accumulator
// gather loop with 4 outstanding 16B loads per thread.

constexpr int D   = 64;
constexpr int N0  = 10;
constexpr int N1  = 25;
constexpr int NN  = N0 * N1;   // 250
constexpr int H1  = 128;
constexpr int H0  = 128;
constexpr int NT  = 256;

__global__ __launch_bounds__(NT, 4) void sage_fused(
    const int*   __restrict__ inputs,   // [B]
    const int*   __restrict__ neigh0,   // [B, 10]
    const int*   __restrict__ neigh1,   // [B, 250]
    const float* __restrict__ embed,    // [NODE_CNT+1, 64]
    const float* __restrict__ W1,       // [128, 128]
    const float* __restrict__ W0,       // [192, 128]
    const float* __restrict__ b0,       // [128]
    float*       __restrict__ out)      // [B, 128]
{
    __shared__ int   s_idx1[NN];        // 250 ints
    __shared__ int   s_idx0[N0];
    __shared__ int   s_in;
    __shared__ float part_nn[16][D];    // 4 KB
    __shared__ float part_en[N0][D];    // 2.5 KB
    __shared__ float xbar[2 * D];       // [mean e_n | mean e_nn]
    __shared__ float x0s[D + H1];       // [e_v | agg0]
    __shared__ float p2[2][H1];

    const int t = threadIdx.x;
    const int b = blockIdx.x;

    // ---- stage indices ----
    if (t < NN)      s_idx1[t] = neigh1[b * NN + t];
    if (t < N0)      s_idx0[t] = neigh0[b * N0 + t];
    if (t == 0)      s_in      = inputs[b];
    __syncthreads();

    // ---- phase 1: gather 261 rows, 16 lanes per 256B row ----
    const int c4   = t & 15;        // 16B chunk within row
    const int s    = t >> 4;        // slot 0..15
    const int cOff = c4 * 4;

    float4 a0 = make_float4(0,0,0,0), a1 = make_float4(0,0,0,0);
    float4 a2 = make_float4(0,0,0,0), a3 = make_float4(0,0,0,0);
    int i = s;
    #pragma unroll 1
    for (; i + 48 < NN; i += 64) {   // 4 independent loads in flight
        const int i0 = s_idx1[i];
        const int i1 = s_idx1[i + 16];
        const int i2 = s_idx1[i + 32];
        const int i3 = s_idx1[i + 48];
        const float4 v0 = *(const float4*)(embed + (size_t)i0 * D + cOff);
        const float4 v1 = *(const float4*)(embed + (size_t)i1 * D + cOff);
        const float4 v2 = *(const float4*)(embed + (size_t)i2 * D + cOff);
        const float4 v3 = *(const float4*)(embed + (size_t)i3 * D + cOff);
        a0.x += v0.x; a0.y += v0.y; a0.z += v0.z; a0.w += v0.w;
        a1.x += v1.x; a1.y += v1.y; a1.z += v1.z; a1.w += v1.w;
        a2.x += v2.x; a2.y += v2.y; a2.z += v2.z; a2.w += v2.w;
        a3.x += v3.x; a3.y += v3.y; a3.z += v3.z; a3.w += v3.w;
    }
    #pragma unroll 1
    for (; i < NN; i += 16) {
        const float4 v = *(const float4*)(embed + (size_t)s_idx1[i] * D + cOff);
        a0.x += v.x; a0.y += v.y; a0.z += v.z; a0.w += v.w;
    }
    a0.x += a1.x + a2.x + a3.x;  a0.y += a1.y + a2.y + a3.y;
    a0.z += a1.z + a2.z + a3.z;  a0.w += a1.w + a2.w + a3.w;
    *(float4*)&part_nn[s][cOff] = a0;

    if (s < N0) {   // one e_n row per slot
        const float4 v = *(const float4*)(embed + (size_t)s_idx0[s] * D + cOff);
        *(float4*)&part_en[s][cOff] = v;
    }
    if (t < 16) {   // e_v row
        const float4 v = *(const float4*)(embed + (size_t)s_in * D + t * 4);
        *(float4*)&x0s[t * 4] = v;
    }
    __syncthreads();

    // ---- reduce partials -> xbar ----
    if (t < D) {
        float snn = 0.f;
        #pragma unroll
        for (int q = 0; q < 16; ++q) snn += part_nn[q][t];
        float sen = 0.f;
        #pragma unroll
        for (int q = 0; q < N0; ++q) sen += part_en[q][t];
        xbar[t]     = sen * (1.0f / N0);
        xbar[D + t] = snn * (1.0f / NN);
    }
    __syncthreads();

    // ---- phase 2a: agg0 = xbar @ W1 (128x128 matvec) ----
    const int j    = t & 127;
    const int half = t >> 7;
    {
        float acc = 0.f;
        const int kbase = half * 64;
        #pragma unroll 4
        for (int k4 = 0; k4 < 16; ++k4) {
            const int k = kbase + k4 * 4;
            const float4 xv = *(const float4*)&xbar[k];
            acc += xv.x * W1[(k + 0) * H1 + j];
            acc += xv.y * W1[(k + 1) * H1 + j];
            acc += xv.z * W1[(k + 2) * H1 + j];
            acc += xv.w * W1[(k + 3) * H1 + j];
        }
        p2[half][j] = acc;
    }
    __syncthreads();
    if (t < H1) x0s[D + t] = p2[0][t] + p2[1][t];
    __syncthreads();

    // ---- phase 2b: h0 = sigmoid(x0 @ W0 + b0) (192x128 matvec) ----
    {
        float acc = 0.f;
        const int kbase = half * 96;
        #pragma unroll 4
        for (int k4 = 0; k4 < 24; ++k4) {
            const int k = kbase + k4 * 4;
            const float4 xv = *(const float4*)&x0s[k];
            acc += xv.x * W0[(k + 0) * H0 + j];
            acc += xv.y * W0[(k + 1) * H0 + j];
            acc += xv.z * W0[(k + 2) * H0 + j];
            acc += xv.w * W0[(k + 3) * H0 + j];
        }
        p2[half][j] = acc;
    }
    __syncthreads();
    if (t < H0) {
        const float v = p2[0][t] + p2[1][t] + b0[t];
        out[(size_t)b * H0 + t] = 1.0f / (1.0f + __expf(-v));
    }
}

extern "C" void kernel_launch(void* const* d_in, const int* in_sizes, int n_in,
                              void* d_out, int out_size, void* d_ws, size_t ws_size,
                              hipStream_t stream) {
    const int*   inputs = (const int*)  d_in[0];
    const int*   neigh0 = (const int*)  d_in[1];
    const int*   neigh1 = (const int*)  d_in[2];
    const float* embed  = (const float*)d_in[3];
    const float* W1     = (const float*)d_in[4];
    const float* W0     = (const float*)d_in[5];
    const float* b0     = (const float*)d_in[6];
    float*       out    = (float*)d_out;

    const int B = in_sizes[0];   // 4096
    sage_fused<<<dim3(B), dim3(NT), 0, stream>>>(
        inputs, neigh0, neigh1, embed, W1, W0, b0, out);
}